// Round 1
// baseline (188.195 us; speedup 1.0000x reference)
//
#include <hip/hip_runtime.h>
#include <hip/hip_bf16.h>

// NA Spatial MSA, fused:  out = attn @ (xw @ (Wv@Wo)) + bo
// Stage-0: WT[n][k] = (Wv@Wo)[k][n] in bf16 (N-major for MFMA B-frags).
// Main: 1 block = 1 window (64 tok x 256 ch), 4 waves, mfma_f32_32x32x16_bf16.

typedef __bf16 bf16x8 __attribute__((ext_vector_type(8)));
typedef __bf16 bf16x4 __attribute__((ext_vector_type(4)));
typedef float  f32x16 __attribute__((ext_vector_type(16)));
typedef float  f32x4  __attribute__((ext_vector_type(4)));

#define MFMA32(a, b, c) __builtin_amdgcn_mfma_f32_32x32x16_bf16(a, b, c, 0, 0, 0)

// ---------------- Stage 0: WT = (Wv @ Wo)^T in bf16 ----------------
__global__ void wfuse_kernel(const float* __restrict__ Wv,
                             const float* __restrict__ Wo,
                             __bf16* __restrict__ WT) {
  const int n = blockIdx.x;    // output channel (col of W)
  const int k = threadIdx.x;   // input channel  (row of W)
  const float* wvrow = Wv + k * 256;
  float acc = 0.f;
#pragma unroll 4
  for (int j = 0; j < 256; j += 4) {
    f32x4 wv = *(const f32x4*)(wvrow + j);
    acc += wv.x * Wo[(j + 0) * 256 + n];   // n uniform per block -> s_load
    acc += wv.y * Wo[(j + 1) * 256 + n];
    acc += wv.z * Wo[(j + 2) * 256 + n];
    acc += wv.w * Wo[(j + 3) * 256 + n];
  }
  WT[n * 256 + k] = (__bf16)acc;
}

// ---------------- Main kernel ----------------
// LDS plan (40 KB): [0,32K) xw[64 tok][256 ch] bf16 swizzled, later reused as
// per-wave zT[64 ch][64 tok] bf16 swizzled; [32K,40K) attn[64][64] bf16 swizzled.
__global__ __launch_bounds__(256, 3)
void na_msa_kernel(const float* __restrict__ x,
                   const float* __restrict__ attn,
                   const __bf16* __restrict__ WT,
                   const float* __restrict__ bo,
                   float* __restrict__ out) {
  __shared__ char lds[40960];
  char* lds_xw = lds;
  char* lds_at = lds + 32768;

  const int t    = threadIdx.x;
  const int lane = t & 63;
  const int wv   = t >> 6;
  const int ln31 = lane & 31;
  const int lh   = lane >> 5;           // 0 or 1 (K-half of the wave)

  const int n  = blockIdx.x;            // window id
  const int wi = n & 31;
  const int hi = (n >> 5) & 31;
  const int b  = n >> 10;
  const long base = (((long)(b * 256 + hi * 8)) * 256 + wi * 8) * 256;
  const float* xp = x + base;

  // ---- stage window x -> bf16 LDS [tok][ch], XOR swizzle (tok&31)<<4 ----
  // window = 8 h-rows, each 8 pixels x 256 ch = 2048 contiguous floats
#pragma unroll
  for (int i = 0; i < 16; ++i) {
    int gi = i * 256 + t;               // float4 index within window (0..4095)
    int rowblk = gi >> 9;               // h-row 0..7
    int f = gi & 511;                   // float4 within the 8KB row
    f32x4 v = *(const f32x4*)(xp + rowblk * 65536 + f * 4);  // coalesced 1KB/wave
    int tok = rowblk * 8 + (f >> 6);
    int ch0 = (f & 63) * 4;
    bf16x4 hv = { (__bf16)v.x, (__bf16)v.y, (__bf16)v.z, (__bf16)v.w };
    int byt = tok * 512 + ((ch0 * 2) ^ ((tok & 31) << 4));
    *(bf16x4*)(lds_xw + byt) = hv;
  }

  // ---- stage attn -> bf16 LDS [64][64], XOR swizzle (row&7)<<4 ----
  const float* ap = attn + (long)n * 4096;
#pragma unroll
  for (int i = 0; i < 4; ++i) {
    int fi = i * 256 + t;               // float4 index 0..1023
    f32x4 v = *(const f32x4*)(ap + fi * 4);
    int row = fi >> 4;
    int k0 = (fi & 15) * 4;
    bf16x4 hv = { (__bf16)v.x, (__bf16)v.y, (__bf16)v.z, (__bf16)v.w };
    int byt = row * 128 + ((k0 * 2) ^ ((row & 7) << 4));
    *(bf16x4*)(lds_at + byt) = hv;
  }
  __syncthreads();

  // ---- GEMM1: z[tok][ch] = xw @ W, K=256. Wave wv owns ch [64*wv, 64*wv+64) ----
  // A-frag: row = tok (lane&31 per m-tile), k = ks*16 + 8*lh + e  (contiguous 16B)
  // B-frag: col = n-channel per lane, k contiguous -> WT[n][k..k+7]
  f32x16 acc00 = {}, acc10 = {}, acc01 = {}, acc11 = {};
  const __bf16* wtp = WT + (wv * 64 + ln31) * 256 + 8 * lh;
#pragma unroll
  for (int ks = 0; ks < 16; ++ks) {
    int kk = ks * 16 + 8 * lh;
    int byt0 = ln31 * 512 + ((kk * 2) ^ (ln31 << 4));
    bf16x8 a0 = *(const bf16x8*)(lds_xw + byt0);            // tok 0..31
    bf16x8 a1 = *(const bf16x8*)(lds_xw + byt0 + 16384);    // tok 32..63
    bf16x8 b0 = *(const bf16x8*)(wtp + ks * 16);            // ch +0..31
    bf16x8 b1 = *(const bf16x8*)(wtp + 8192 + ks * 16);     // ch +32..63
    acc00 = MFMA32(a0, b0, acc00);
    acc10 = MFMA32(a1, b0, acc10);
    acc01 = MFMA32(a0, b1, acc01);
    acc11 = MFMA32(a1, b1, acc11);
  }
  __syncthreads();   // everyone done reading lds_xw; reuse it for per-wave zT

  // ---- write z^T per wave: zT[chl][tok] bf16, XOR swizzle (chl&7)<<4 ----
  // C/D layout (32x32): col = lane&31, row = (reg&3) + 8*(reg>>2) + 4*(lane>>5)
  char* ztw = lds + (wv << 13);   // 8KB per wave, aliases lds_xw
#define ZWRITE(ACC, MT, NTL) do {                                         \
    int chl = (NTL) * 32 + ln31;                                          \
    int rb = chl * 128;                                                   \
    int sw = (chl & 7) << 4;                                              \
    _Pragma("unroll")                                                     \
    for (int g = 0; g < 4; ++g) {                                         \
      int tok0 = (MT) * 32 + g * 8 + 4 * lh;                              \
      bf16x4 hv = { (__bf16)ACC[4 * g + 0], (__bf16)ACC[4 * g + 1],       \
                    (__bf16)ACC[4 * g + 2], (__bf16)ACC[4 * g + 3] };     \
      *(bf16x4*)(ztw + rb + ((tok0 * 2) ^ sw)) = hv;                      \
    } } while (0)
  ZWRITE(acc00, 0, 0); ZWRITE(acc01, 0, 1);
  ZWRITE(acc10, 1, 0); ZWRITE(acc11, 1, 1);

  // ---- GEMM2: out[tok][ch] = attn @ z, K=64 (wave-local zT) ----
  f32x16 o00 = {}, o10 = {}, o01 = {}, o11 = {};
#pragma unroll
  for (int ks = 0; ks < 4; ++ks) {
    int kk = ks * 16 + 8 * lh;
    int ab0 = ln31 * 128 + ((kk * 2) ^ ((ln31 & 7) << 4));
    bf16x8 a0 = *(const bf16x8*)(lds_at + ab0);             // out-tok 0..31
    bf16x8 a1 = *(const bf16x8*)(lds_at + ab0 + 4096);      // out-tok 32..63
    bf16x8 b0 = *(const bf16x8*)(ztw + ab0);                // chl 0..31
    bf16x8 b1 = *(const bf16x8*)(ztw + ab0 + 4096);         // chl 32..63
    o00 = MFMA32(a0, b0, o00);
    o10 = MFMA32(a1, b0, o10);
    o01 = MFMA32(a0, b1, o01);
    o11 = MFMA32(a1, b1, o11);
  }

  // ---- epilogue: + bo, scatter to (b,h,w,c). lanes 0-31 = consecutive ch ----
  float* op = out + base;
  float bv0 = bo[wv * 64 + ln31];
  float bv1 = bo[wv * 64 + 32 + ln31];
#define OWRITE(ACC, MT, NTL) do {                                         \
    int ch = wv * 64 + (NTL) * 32 + ln31;                                 \
    float bv = (NTL) ? bv1 : bv0;                                         \
    _Pragma("unroll")                                                     \
    for (int r = 0; r < 16; ++r) {                                        \
      int tok = (MT) * 32 + (r & 3) + 8 * (r >> 2) + 4 * lh;              \
      op[(tok >> 3) * 65536 + (tok & 7) * 256 + ch] = ACC[r] + bv;        \
    } } while (0)
  OWRITE(o00, 0, 0); OWRITE(o01, 0, 1);
  OWRITE(o10, 1, 0); OWRITE(o11, 1, 1);
}

extern "C" void kernel_launch(void* const* d_in, const int* in_sizes, int n_in,
                              void* d_out, int out_size, void* d_ws, size_t ws_size,
                              hipStream_t stream) {
  const float* x    = (const float*)d_in[0];
  const float* attn = (const float*)d_in[1];
  const float* Wv   = (const float*)d_in[2];
  const float* Wo   = (const float*)d_in[3];
  const float* bo   = (const float*)d_in[4];
  float* out = (float*)d_out;
  __bf16* WT = (__bf16*)d_ws;   // 256*256*2 = 128 KB scratch

  wfuse_kernel<<<256, 256, 0, stream>>>(Wv, Wo, WT);
  na_msa_kernel<<<4096, 256, 0, stream>>>(x, attn, WT, bo, out);
}

// Round 2
// 176.373 us; speedup vs baseline: 1.0670x; 1.0670x over previous
//
#include <hip/hip_runtime.h>
#include <hip/hip_bf16.h>

// NA Spatial MSA, fused:  out = attn @ (xw @ (Wv@Wo)) + bo
// Stage-0: WT[n][k] = (Wv@Wo)[k][n] in bf16 (N-major for MFMA B-frags).
// Main: 1 block = 1 window (64 tok x 256 ch), 8 waves (wave owns 32 ch),
// mfma_f32_32x32x16_bf16. __launch_bounds__(512,8) -> VGPR<=64 -> 4 blk/CU.

typedef __bf16 bf16x8 __attribute__((ext_vector_type(8)));
typedef __bf16 bf16x4 __attribute__((ext_vector_type(4)));
typedef float  f32x16 __attribute__((ext_vector_type(16)));
typedef float  f32x4  __attribute__((ext_vector_type(4)));

#define MFMA32(a, b, c) __builtin_amdgcn_mfma_f32_32x32x16_bf16(a, b, c, 0, 0, 0)

// ---------------- Stage 0: WT = (Wv @ Wo)^T in bf16 ----------------
__global__ void wfuse_kernel(const float* __restrict__ Wv,
                             const float* __restrict__ Wo,
                             __bf16* __restrict__ WT) {
  const int n = blockIdx.x;    // output channel (col of W)
  const int k = threadIdx.x;   // input channel  (row of W)
  const float* wvrow = Wv + k * 256;
  float acc = 0.f;
#pragma unroll 4
  for (int j = 0; j < 256; j += 4) {
    f32x4 wv = *(const f32x4*)(wvrow + j);
    acc += wv.x * Wo[(j + 0) * 256 + n];   // n uniform per block -> s_load
    acc += wv.y * Wo[(j + 1) * 256 + n];
    acc += wv.z * Wo[(j + 2) * 256 + n];
    acc += wv.w * Wo[(j + 3) * 256 + n];
  }
  WT[n * 256 + k] = (__bf16)acc;
}

// ---------------- Main kernel ----------------
// LDS plan (40 KB): [0,32K) xw[64 tok][256 ch] bf16 swizzled, later reused as
// per-wave zT[32 ch][64 tok] bf16 swizzled (4KB/wave); [32K,40K) attn[64][64].
__global__ __launch_bounds__(512, 8)
void na_msa_kernel(const float* __restrict__ x,
                   const float* __restrict__ attn,
                   const __bf16* __restrict__ WT,
                   const float* __restrict__ bo,
                   float* __restrict__ out) {
  __shared__ char lds[40960];
  char* lds_xw = lds;
  char* lds_at = lds + 32768;

  const int t    = threadIdx.x;
  const int lane = t & 63;
  const int wv   = t >> 6;              // 0..7, wave owns ch [32wv, 32wv+32)
  const int ln31 = lane & 31;
  const int lh   = lane >> 5;           // 0 or 1 (K-half of the wave)

  const int n  = blockIdx.x;            // window id
  const int wi = n & 31;
  const int hi = (n >> 5) & 31;
  const int b  = n >> 10;
  const long base = (((long)(b * 256 + hi * 8)) * 256 + wi * 8) * 256;
  const float* xp = x + base;

  // ---- stage window x -> bf16 LDS [tok][ch], XOR swizzle (tok&31)<<4 ----
  // window = 8 h-rows, each 8 pixels x 256 ch = 2048 contiguous floats
#pragma unroll
  for (int i = 0; i < 8; ++i) {
    int gi = i * 512 + t;               // float4 index within window (0..4095)
    int rowblk = gi >> 9;               // h-row 0..7
    int f = gi & 511;                   // float4 within the 8KB row
    f32x4 v = *(const f32x4*)(xp + rowblk * 65536 + f * 4);  // coalesced
    int tok = rowblk * 8 + (f >> 6);
    int ch0 = (f & 63) * 4;
    bf16x4 hv = { (__bf16)v.x, (__bf16)v.y, (__bf16)v.z, (__bf16)v.w };
    int byt = tok * 512 + ((ch0 * 2) ^ ((tok & 31) << 4));
    *(bf16x4*)(lds_xw + byt) = hv;
  }

  // ---- stage attn -> bf16 LDS [64][64], XOR swizzle (row&7)<<4 ----
  const float* ap = attn + (long)n * 4096;
#pragma unroll
  for (int i = 0; i < 2; ++i) {
    int fi = i * 512 + t;               // float4 index 0..1023
    f32x4 v = *(const f32x4*)(ap + fi * 4);
    int row = fi >> 4;
    int k0 = (fi & 15) * 4;
    bf16x4 hv = { (__bf16)v.x, (__bf16)v.y, (__bf16)v.z, (__bf16)v.w };
    int byt = row * 128 + ((k0 * 2) ^ ((row & 7) << 4));
    *(bf16x4*)(lds_at + byt) = hv;
  }
  __syncthreads();

  // ---- GEMM1: z[tok][ch] = xw @ W, K=256. Wave wv owns ch [32wv, 32wv+32) ----
  // A-frag: row = tok (lane&31 per m-tile), k = ks*16 + 8*lh + e (contig 16B)
  // B-frag: col = n-channel per lane, k contiguous -> WT[n][k..k+7]
  f32x16 acc0 = {}, acc1 = {};
  const __bf16* wtp = WT + (wv * 32 + ln31) * 256 + 8 * lh;
#pragma unroll
  for (int ks = 0; ks < 16; ++ks) {
    int kk = ks * 16 + 8 * lh;
    int byt0 = ln31 * 512 + ((kk * 2) ^ (ln31 << 4));
    bf16x8 a0 = *(const bf16x8*)(lds_xw + byt0);            // tok 0..31
    bf16x8 a1 = *(const bf16x8*)(lds_xw + byt0 + 16384);    // tok 32..63
    bf16x8 b0 = *(const bf16x8*)(wtp + ks * 16);            // ch block
    acc0 = MFMA32(a0, b0, acc0);
    acc1 = MFMA32(a1, b0, acc1);
  }
  __syncthreads();   // everyone done reading lds_xw; reuse it for per-wave zT

  // ---- write z^T per wave: zT[chl][tok] bf16, XOR swizzle (chl&7)<<4 ----
  // C/D layout (32x32): col = lane&31, row = (reg&3) + 8*(reg>>2) + 4*(lane>>5)
  char* ztw = lds + (wv << 12);   // 4KB per wave, aliases lds_xw
  {
    int rb = ln31 * 128;          // chl = ln31
    int sw = (ln31 & 7) << 4;
#pragma unroll
    for (int g = 0; g < 4; ++g) {
      int tok0 = g * 8 + 4 * lh;  // acc0: toks 0..31
      bf16x4 h0 = { (__bf16)acc0[4 * g + 0], (__bf16)acc0[4 * g + 1],
                    (__bf16)acc0[4 * g + 2], (__bf16)acc0[4 * g + 3] };
      *(bf16x4*)(ztw + rb + ((tok0 * 2) ^ sw)) = h0;
      int tok1 = 32 + g * 8 + 4 * lh;  // acc1: toks 32..63
      bf16x4 h1 = { (__bf16)acc1[4 * g + 0], (__bf16)acc1[4 * g + 1],
                    (__bf16)acc1[4 * g + 2], (__bf16)acc1[4 * g + 3] };
      *(bf16x4*)(ztw + rb + ((tok1 * 2) ^ sw)) = h1;
    }
  }

  // ---- GEMM2: out[tok][ch] = attn @ z, K=64 (wave-local zT) ----
  f32x16 o0 = {}, o1 = {};
#pragma unroll
  for (int ks = 0; ks < 4; ++ks) {
    int kk = ks * 16 + 8 * lh;
    int ab0 = ln31 * 128 + ((kk * 2) ^ ((ln31 & 7) << 4));
    bf16x8 a0 = *(const bf16x8*)(lds_at + ab0);             // out-tok 0..31
    bf16x8 a1 = *(const bf16x8*)(lds_at + ab0 + 4096);      // out-tok 32..63
    bf16x8 b0 = *(const bf16x8*)(ztw + ab0);                // wave's 32 chl
    o0 = MFMA32(a0, b0, o0);
    o1 = MFMA32(a1, b0, o1);
  }

  // ---- epilogue: + bo, scatter to (b,h,w,c). lanes 0-31 = consecutive ch ----
  float* op = out + base;
  const int ch = wv * 32 + ln31;
  const float bv = bo[ch];
#pragma unroll
  for (int r = 0; r < 16; ++r) {
    int tok = (r & 3) + 8 * (r >> 2) + 4 * lh;              // o0: toks 0..31
    op[(tok >> 3) * 65536 + (tok & 7) * 256 + ch] = o0[r] + bv;
  }
#pragma unroll
  for (int r = 0; r < 16; ++r) {
    int tok = 32 + (r & 3) + 8 * (r >> 2) + 4 * lh;         // o1: toks 32..63
    op[(tok >> 3) * 65536 + (tok & 7) * 256 + ch] = o1[r] + bv;
  }
}

extern "C" void kernel_launch(void* const* d_in, const int* in_sizes, int n_in,
                              void* d_out, int out_size, void* d_ws, size_t ws_size,
                              hipStream_t stream) {
  const float* x    = (const float*)d_in[0];
  const float* attn = (const float*)d_in[1];
  const float* Wv   = (const float*)d_in[2];
  const float* Wo   = (const float*)d_in[3];
  const float* bo   = (const float*)d_in[4];
  float* out = (float*)d_out;
  __bf16* WT = (__bf16*)d_ws;   // 256*256*2 = 128 KB scratch

  wfuse_kernel<<<256, 256, 0, stream>>>(Wv, Wo, WT);
  na_msa_kernel<<<4096, 512, 0, stream>>>(x, attn, WT, bo, out);
}